// Round 9
// baseline (285.657 us; speedup 1.0000x reference)
//
#include <hip/hip_runtime.h>
#include <hip/hip_bf16.h>
#include <math.h>

#define B 16
#define N 600
#define DIM 128
#define HEADS 8
#define DH 32
#define INNER 256
#define D3 384
#define NC_H (D3*INNER)   /* 98304 */
#define NC_O (INNER*DIM)  /* 32768 */

typedef _Float16 f16x8 __attribute__((ext_vector_type(8)));
typedef float    f32x4 __attribute__((ext_vector_type(4)));

// ---------------- ws layout (float offsets) ----------------  ws = 576 MiB
// t2 : 0 (unused)   s2 : 6144 (unused)   h : 10240   ow : 1583104
// t1 : 2107392  s1 : 2113536
// ao : 2117632   qh : 4575232(half)  kh : 5804032(half)  vt : 7032832(half)
// t2T: 8343552  [384][16]      s2T: 8349696  [256][16]
// pH : 8353792  (8 x 16 x 98304  = 12,582,912)
// pO : 20936704 (16 x 16 x 32768 =  8,388,608)   end 29,325,312 f32 = 117 MB
// No aliasing anywhere.

__global__ void k_chain1(const float* __restrict__ resolution,
                         const float* __restrict__ framerate,
                         const float* __restrict__ W1, const float* __restrict__ b1,
                         const float* __restrict__ V1, const float* __restrict__ c1,
                         float* __restrict__ t1, float* __restrict__ s1)
{
    __shared__ float fr[B], re[B];
    int j = threadIdx.x;   // 384 threads
    if (j < B) { fr[j] = framerate[j]; re[j] = resolution[j]; }
    __syncthreads();
    {
        float w0 = W1[j], w1 = W1[D3 + j], bb = b1[j];
        for (int b = 0; b < B; ++b) t1[b*D3 + j] = fr[b]*w0 + re[b]*w1 + bb;
    }
    if (j < INNER) {
        float w0 = V1[j], w1 = V1[INNER + j], bb = c1[j];
        for (int b = 0; b < B; ++b) s1[b*INNER + j] = fr[b]*w0 + re[b]*w1 + bb;
    }
}

// t2T[j][b] / s2T[j][b]: k-major activations for k_hyper4's scalar loads
__global__ void k_chain2(const float* __restrict__ t1, const float* __restrict__ s1,
                         const float* __restrict__ W2, const float* __restrict__ b2,
                         const float* __restrict__ V2, const float* __restrict__ c2,
                         float* __restrict__ t2T, float* __restrict__ s2T)
{
    __shared__ float in_s[B*D3];
    int bid = blockIdx.x, tid = threadIdx.x;
    if (bid < 24) {
        for (int i = tid; i < B*D3; i += 256) in_s[i] = t1[i];
        __syncthreads();
        int flat = bid*256 + tid;
        int b = flat / D3, j = flat - b*D3;
        float acc = b2[j];
        #pragma unroll 4
        for (int kk = 0; kk < D3; ++kk)
            acc = fmaf(in_s[b*D3 + kk], W2[kk*D3 + j], acc);
        t2T[j*B + b] = acc;
    } else {
        for (int i = tid; i < B*INNER; i += 256) in_s[i] = s1[i];
        __syncthreads();
        int flat = (bid - 24)*256 + tid;
        int b = flat / INNER, j = flat - b*INNER;
        float acc = c2[j];
        #pragma unroll 4
        for (int kk = 0; kk < INNER; ++kk)
            acc = fmaf(in_s[b*INNER + kk], V2[kk*INNER + j], acc);
        s2T[j*B + b] = acc;
    }
}

// Streaming split-K GEMM: thread = 4 cols (float4), block = 1024 cols, KSG splits.
// Two-group (4-row) software pipeline with NAMED register sets (rule-#20 safe):
// 8 float4 loads in flight per wave (8 KB) -> covers loaded-HBM latency.
// Activations via wave-uniform s_load from tT[k][16].  KR % 8 == 0 required.
template<int K, int NC, int KSG>
__global__ __launch_bounds__(256) void k_hyper4(const float* __restrict__ tT,
                                                const float* __restrict__ W,
                                                float* __restrict__ partial)
{
    constexpr int KR = K / KSG;
    constexpr int NCB = NC / 1024;
    int tid = threadIdx.x;
    int cb = blockIdx.x % NCB, ksg = blockIdx.x / NCB;
    int col = cb*1024 + tid*4;
    const float* wp = W + (size_t)(ksg*KR)*NC + col;
    const float* tp = tT + ksg*KR*B;

    float4 acc[B];
    #pragma unroll
    for (int b = 0; b < B; ++b) acc[b] = make_float4(0.f, 0.f, 0.f, 0.f);

    // prologue: rows 0..3 -> A, rows 4..7 -> Bs
    float4 A0 = *(const float4*)(wp + (size_t)0*NC);
    float4 A1 = *(const float4*)(wp + (size_t)1*NC);
    float4 A2 = *(const float4*)(wp + (size_t)2*NC);
    float4 A3 = *(const float4*)(wp + (size_t)3*NC);
    float4 B0 = *(const float4*)(wp + (size_t)4*NC);
    float4 B1 = *(const float4*)(wp + (size_t)5*NC);
    float4 B2 = *(const float4*)(wp + (size_t)6*NC);
    float4 B3 = *(const float4*)(wp + (size_t)7*NC);

    for (int g8 = 0; g8 < KR; g8 += 8) {
        {   // compute rows g8..g8+3 (A set); prefetch rows g8+8..g8+11 into A
            float4 c0 = A0, c1 = A1, c2 = A2, c3 = A3;
            int pr = (g8 + 8 < KR) ? (g8 + 8) : 0;
            const float* wn = wp + (size_t)pr*NC;
            A0 = *(const float4*)(wn);
            A1 = *(const float4*)(wn + (size_t)1*NC);
            A2 = *(const float4*)(wn + (size_t)2*NC);
            A3 = *(const float4*)(wn + (size_t)3*NC);
            const float* trow = tp + g8*B;
            #pragma unroll
            for (int b = 0; b < B; ++b) {
                float ta = trow[b], tb = trow[B+b], tc = trow[2*B+b], td = trow[3*B+b];
                acc[b].x = fmaf(ta, c0.x, fmaf(tb, c1.x, fmaf(tc, c2.x, fmaf(td, c3.x, acc[b].x))));
                acc[b].y = fmaf(ta, c0.y, fmaf(tb, c1.y, fmaf(tc, c2.y, fmaf(td, c3.y, acc[b].y))));
                acc[b].z = fmaf(ta, c0.z, fmaf(tb, c1.z, fmaf(tc, c2.z, fmaf(td, c3.z, acc[b].z))));
                acc[b].w = fmaf(ta, c0.w, fmaf(tb, c1.w, fmaf(tc, c2.w, fmaf(td, c3.w, acc[b].w))));
            }
        }
        {   // compute rows g8+4..g8+7 (B set); prefetch rows g8+12..g8+15 into Bs
            float4 c0 = B0, c1 = B1, c2 = B2, c3 = B3;
            int pr = (g8 + 12 < KR) ? (g8 + 12) : 0;
            const float* wn = wp + (size_t)pr*NC;
            B0 = *(const float4*)(wn);
            B1 = *(const float4*)(wn + (size_t)1*NC);
            B2 = *(const float4*)(wn + (size_t)2*NC);
            B3 = *(const float4*)(wn + (size_t)3*NC);
            const float* trow = tp + (g8 + 4)*B;
            #pragma unroll
            for (int b = 0; b < B; ++b) {
                float ta = trow[b], tb = trow[B+b], tc = trow[2*B+b], td = trow[3*B+b];
                acc[b].x = fmaf(ta, c0.x, fmaf(tb, c1.x, fmaf(tc, c2.x, fmaf(td, c3.x, acc[b].x))));
                acc[b].y = fmaf(ta, c0.y, fmaf(tb, c1.y, fmaf(tc, c2.y, fmaf(td, c3.y, acc[b].y))));
                acc[b].z = fmaf(ta, c0.z, fmaf(tb, c1.z, fmaf(tc, c2.z, fmaf(td, c3.z, acc[b].z))));
                acc[b].w = fmaf(ta, c0.w, fmaf(tb, c1.w, fmaf(tc, c2.w, fmaf(td, c3.w, acc[b].w))));
            }
        }
    }
    float* pp = partial + (size_t)ksg*B*NC + col;
    #pragma unroll
    for (int b = 0; b < B; ++b)
        *(float4*)(pp + (size_t)b*NC) = acc[b];
}

template<int NC, int KSG>
__global__ __launch_bounds__(256) void k_reduce(const float* __restrict__ partial,
                                                const float* __restrict__ bias,
                                                float* __restrict__ out)
{
    int i = blockIdx.x*256 + threadIdx.x;
    int col = i % NC;
    float s = bias[col];
    #pragma unroll
    for (int ks = 0; ks < KSG; ++ks) s += partial[(size_t)ks*B*NC + i];
    out[i] = s;
}

// softmax along R-axis of data[b][R][CPB]; COLS*GROUPS = 256 threads
template<int R, int CPB, int COLS, int GROUPS>
__global__ __launch_bounds__(256) void k_softmax2(float* __restrict__ data)
{
    constexpr int RPT = R / GROUPS;
    __shared__ float red[GROUPS][COLS];
    int tid = threadIdx.x;
    int col = tid % COLS, g = tid / COLS;
    int nb = CPB / COLS;
    int b = blockIdx.x / nb, cb = blockIdx.x % nb;
    float* p = data + (size_t)b*R*CPB + (size_t)g*RPT*CPB + cb*COLS + col;
    float vals[RPT];
    float m = -1e30f;
    #pragma unroll 4
    for (int r = 0; r < RPT; ++r) { vals[r] = p[(size_t)r*CPB]; m = fmaxf(m, vals[r]); }
    red[g][col] = m;
    __syncthreads();
    float M = red[0][col];
    #pragma unroll
    for (int gg = 1; gg < GROUPS; ++gg) M = fmaxf(M, red[gg][col]);
    __syncthreads();
    float s = 0.f;
    #pragma unroll 4
    for (int r = 0; r < RPT; ++r) { vals[r] = __expf(vals[r] - M); s += vals[r]; }
    red[g][col] = s;
    __syncthreads();
    float S = 0.f;
    #pragma unroll
    for (int gg = 0; gg < GROUPS; ++gg) S += red[gg][col];
    float inv = 1.f / S;
    #pragma unroll 4
    for (int r = 0; r < RPT; ++r) p[(size_t)r*CPB] = vals[r] * inv;
}

// x @ qkvw -> q,k (fp16 row-major, q pre-scaled) and v (fp16 transposed [d][n])
__global__ __launch_bounds__(768) void k_proj(const float* __restrict__ x,
                                              const float* __restrict__ qkvw,
                                              _Float16* __restrict__ qh,
                                              _Float16* __restrict__ kh,
                                              _Float16* __restrict__ vt)
{
    __shared__ float4 xs4[24*32];
    int b = blockIdx.x / 25, t0 = (blockIdx.x % 25)*24;
    int tid = threadIdx.x;
    const float4* xp4 = (const float4*)(x + ((size_t)b*N + t0)*DIM);
    xs4[tid] = xp4[tid];              // 24*32 = 768 = blockDim
    __syncthreads();
    float acc[24];
    #pragma unroll
    for (int r = 0; r < 24; ++r) acc[r] = 0.f;
    const float* wp = qkvw + (size_t)b*NC_H + tid;
    for (int d4 = 0; d4 < 32; ++d4) {
        float w0 = wp[(size_t)(4*d4)*768];
        float w1 = wp[(size_t)(4*d4+1)*768];
        float w2 = wp[(size_t)(4*d4+2)*768];
        float w3 = wp[(size_t)(4*d4+3)*768];
        #pragma unroll
        for (int r = 0; r < 24; ++r) {
            float4 xv = xs4[r*32 + d4];
            acc[r] = fmaf(xv.x, w0, fmaf(xv.y, w1, fmaf(xv.z, w2, fmaf(xv.w, w3, acc[r]))));
        }
    }
    int which = tid >> 8;
    int e = tid & 255;
    int hh = e >> 5, dh = e & 31;
    const float scale = 0.17677669529663687f;   // 32^-0.5 folded into Q
    if (which == 0) {
        _Float16* qp = qh + ((size_t)(b*HEADS + hh)*N + t0)*DH + dh;
        #pragma unroll
        for (int r = 0; r < 24; ++r) qp[r*DH] = (_Float16)(acc[r]*scale);
    } else if (which == 1) {
        _Float16* kp = kh + ((size_t)(b*HEADS + hh)*N + t0)*DH + dh;
        #pragma unroll
        for (int r = 0; r < 24; ++r) kp[r*DH] = (_Float16)acc[r];
    } else {
        _Float16* vp = vt + ((size_t)(b*HEADS + hh)*DH + dh)*640 + t0;
        #pragma unroll
        for (int r = 0; r < 24; ++r) vp[r] = (_Float16)acc[r];
        if (t0 == 576) {
            // cols 600..639 must be finite (ws poison is 0xAA -> finite fp16, but
            // keep deterministic zeros so PV tail contributes exactly 0)
            #pragma unroll
            for (int r = 24; r < 64; ++r) vp[r] = (_Float16)0.f;
        }
    }
}

static __device__ inline unsigned pk2(float a, float b) {
    auto t = __builtin_amdgcn_cvt_pkrtz(a, b);   // __fp16 ext_vector(2)
    return __builtin_bit_cast(unsigned, t);
}

// MFMA flash attention v4.  Block = 4 waves = 4 heads sharing one (b, q-chunk);
// wave = 16 q-rows x 600 keys.  Head-independent mask tile [16][64] f32 staged
// cooperatively in LDS, double-buffered.  S^T = mfma(K, Q^T), out^T = mfma(V^T, P^T).
__global__ __launch_bounds__(256) void k_attn4(const _Float16* __restrict__ qh,
                                               const _Float16* __restrict__ kh,
                                               const _Float16* __restrict__ vt,
                                               const float* __restrict__ mask,
                                               float* __restrict__ ao)
{
    __shared__ float mbuf[2][16][65];
    __shared__ __align__(16) _Float16 plds[4][16][72];
    int bid = blockIdx.x;
    int qc = bid / 32, r2 = bid % 32;
    int b = r2 >> 1, hg = r2 & 1;
    int tid = threadIdx.x;
    int w = tid >> 6, lane = tid & 63;
    int ql = lane & 15, g = lane >> 4;
    int h = hg*4 + w;
    int q0 = qc*16;
    size_t bh = (size_t)(b*HEADS + h);
    const _Float16* Qb  = qh + bh*(size_t)(N*DH);
    const _Float16* Kb  = kh + bh*(size_t)(N*DH);
    const _Float16* Vtb = vt + bh*(size_t)(DH*640);

    int qrow = q0 + ql;
    int qr = qrow > 599 ? 599 : qrow;
    f16x8 qf = *(const f16x8*)(Qb + (size_t)qr*DH + g*8);

    int rl = w*4 + (lane >> 4);          // local tile row 0..15
    int mcol = (lane & 15)*4;            // float col 0..60
    int mgr = q0 + rl; if (mgr > 599) mgr = 599;
    const float* mgp = mask + ((size_t)b*N + mgr)*N;

    float M = -1e30f, S = 0.f;
    f32x4 acc[2];
    acc[0] = (f32x4){0.f,0.f,0.f,0.f};
    acc[1] = (f32x4){0.f,0.f,0.f,0.f};

    {
        int c0 = mcol; if (c0 > 596) c0 = 596;
        float4 mv = *(const float4*)(mgp + c0);
        mbuf[0][rl][mcol+0] = mv.x;
        mbuf[0][rl][mcol+1] = mv.y;
        mbuf[0][rl][mcol+2] = mv.z;
        mbuf[0][rl][mcol+3] = mv.w;
    }
    __syncthreads();

    for (int c = 0; c < 10; ++c) {
        int k0 = c*64;
        int cur = c & 1;
        float4 mnext;
        if (c < 9) {
            int cg = (c+1)*64 + mcol; if (cg > 596) cg = 596;
            mnext = *(const float4*)(mgp + cg);
        }
        f32x4 st[4];
        #pragma unroll
        for (int t = 0; t < 4; ++t) {
            int kr = k0 + 16*t + ql; if (kr > 599) kr = 599;
            f16x8 kf = *(const f16x8*)(Kb + (size_t)kr*DH + g*8);
            st[t] = __builtin_amdgcn_mfma_f32_16x16x32_f16(
                kf, qf, (f32x4){0.f,0.f,0.f,0.f}, 0, 0, 0);
        }
        float tm = -1e30f;
        #pragma unroll
        for (int t = 0; t < 4; ++t) {
            #pragma unroll
            for (int r = 0; r < 4; ++r) {
                int key = k0 + 16*t + 4*g + r;
                float sv = st[t][r];
                if (key >= N) sv = -1e30f;
                st[t][r] = sv;
                tm = fmaxf(tm, sv);
            }
        }
        tm = fmaxf(tm, __shfl_xor(tm, 16));
        tm = fmaxf(tm, __shfl_xor(tm, 32));
        float Mn = fmaxf(M, tm);
        float scl = __expf(M - Mn);
        M = Mn;
        S *= scl;
        acc[0] *= scl;
        acc[1] *= scl;
        float ssum = 0.f;
        #pragma unroll
        for (int t = 0; t < 4; ++t) {
            int cb4 = 16*t + 4*g;
            float e0 = __expf(st[t][0] - Mn);
            float e1 = __expf(st[t][1] - Mn);
            float e2 = __expf(st[t][2] - Mn);
            float e3 = __expf(st[t][3] - Mn);
            ssum += (e0 + e1) + (e2 + e3);
            float m0 = mbuf[cur][ql][cb4+0];
            float m1 = mbuf[cur][ql][cb4+1];
            float m2 = mbuf[cur][ql][cb4+2];
            float m3 = mbuf[cur][ql][cb4+3];
            *(unsigned*)&plds[w][ql][cb4]     = pk2(e0*m0, e1*m1);
            *(unsigned*)&plds[w][ql][cb4 + 2] = pk2(e2*m2, e3*m3);
        }
        ssum += __shfl_xor(ssum, 16);
        ssum += __shfl_xor(ssum, 32);
        S += ssum;
        #pragma unroll
        for (int win = 0; win < 2; ++win) {
            f16x8 pf = *(const f16x8*)&plds[w][ql][win*32 + g*8];
            #pragma unroll
            for (int dt = 0; dt < 2; ++dt) {
                f16x8 vf = *(const f16x8*)(Vtb + (size_t)(dt*16 + ql)*640 + k0 + win*32 + g*8);
                acc[dt] = __builtin_amdgcn_mfma_f32_16x16x32_f16(vf, pf, acc[dt], 0, 0, 0);
            }
        }
        if (c < 9) {
            int nb = cur ^ 1;
            mbuf[nb][rl][mcol+0] = mnext.x;
            mbuf[nb][rl][mcol+1] = mnext.y;
            mbuf[nb][rl][mcol+2] = mnext.z;
            mbuf[nb][rl][mcol+3] = mnext.w;
        }
        __syncthreads();
    }

    if (qrow < N) {
        float inv = 1.f / S;
        float* o = ao + ((size_t)b*N + qrow)*INNER + h*DH;
        #pragma unroll
        for (int dt = 0; dt < 2; ++dt)
            #pragma unroll
            for (int r = 0; r < 4; ++r)
                o[dt*16 + 4*g + r] = acc[dt][r] * inv;
    }
}

__global__ __launch_bounds__(128) void k_final(const float* __restrict__ ao,
                                               const float* __restrict__ ow,
                                               float* __restrict__ out)
{
    __shared__ float4 os4[12*64];
    int b = blockIdx.x / 50, t0 = (blockIdx.x % 50)*12;
    int tid = threadIdx.x;
    const float4* ap4 = (const float4*)(ao + ((size_t)b*N + t0)*INNER);
    for (int i = tid; i < 12*64; i += 128) os4[i] = ap4[i];
    __syncthreads();
    float acc[12];
    #pragma unroll
    for (int r = 0; r < 12; ++r) acc[r] = 0.f;
    const float* wp = ow + (size_t)b*NC_O + tid;
    for (int i4 = 0; i4 < 64; ++i4) {
        float w0 = wp[(size_t)(4*i4)*DIM];
        float w1 = wp[(size_t)(4*i4+1)*DIM];
        float w2 = wp[(size_t)(4*i4+2)*DIM];
        float w3 = wp[(size_t)(4*i4+3)*DIM];
        #pragma unroll
        for (int r = 0; r < 12; ++r) {
            float4 av = os4[r*64 + i4];
            acc[r] = fmaf(av.x, w0, fmaf(av.y, w1, fmaf(av.z, w2, fmaf(av.w, w3, acc[r]))));
        }
    }
    float* op = out + ((size_t)b*N + t0)*DIM + tid;
    #pragma unroll
    for (int r = 0; r < 12; ++r) op[r*DIM] = acc[r];
}

extern "C" void kernel_launch(void* const* d_in, const int* in_sizes, int n_in,
                              void* d_out, int out_size, void* d_ws, size_t ws_size,
                              hipStream_t stream)
{
    const float* x          = (const float*)d_in[0];
    const float* mask       = (const float*)d_in[1];
    const float* resolution = (const float*)d_in[2];
    const float* framerate  = (const float*)d_in[3];
    const float* W1 = (const float*)d_in[4];
    const float* b1 = (const float*)d_in[5];
    const float* W2 = (const float*)d_in[6];
    const float* b2 = (const float*)d_in[7];
    const float* W3 = (const float*)d_in[8];
    const float* b3 = (const float*)d_in[9];
    const float* V1 = (const float*)d_in[10];
    const float* c1 = (const float*)d_in[11];
    const float* V2 = (const float*)d_in[12];
    const float* c2 = (const float*)d_in[13];
    const float* V3 = (const float*)d_in[14];
    const float* c3 = (const float*)d_in[15];

    float* ws = (float*)d_ws;
    float* h   = ws + 10240;
    float* ow  = ws + 1583104;
    float* t1  = ws + 2107392;
    float* s1  = ws + 2113536;
    float* ao  = ws + 2117632;
    _Float16* qh = (_Float16*)(ws + 4575232);
    _Float16* kh = (_Float16*)(ws + 5804032);
    _Float16* vt = (_Float16*)(ws + 7032832);
    float* t2T = ws + 8343552;
    float* s2T = ws + 8349696;
    float* pH  = ws + 8353792;              // 8 x 1,572,864
    float* pO  = ws + 20936704;             // 16 x 524,288
    float* out = (float*)d_out;

    hipLaunchKernelGGL(k_chain1, dim3(1), dim3(384), 0, stream,
                       resolution, framerate, W1, b1, V1, c1, t1, s1);
    hipLaunchKernelGGL(k_chain2, dim3(40), dim3(256), 0, stream,
                       t1, s1, W2, b2, V2, c2, t2T, s2T);
    hipLaunchKernelGGL((k_hyper4<D3, NC_H, 8>), dim3((NC_H/1024)*8), dim3(256), 0, stream,
                       t2T, W3, pH);
    hipLaunchKernelGGL((k_hyper4<INNER, NC_O, 16>), dim3((NC_O/1024)*16), dim3(256), 0, stream,
                       s2T, V3, pO);
    hipLaunchKernelGGL((k_reduce<NC_H, 8>), dim3(B*NC_H/256), dim3(256), 0, stream,
                       pH, b3, h);
    hipLaunchKernelGGL((k_reduce<NC_O, 16>), dim3(B*NC_O/256), dim3(256), 0, stream,
                       pO, c3, ow);
    hipLaunchKernelGGL((k_softmax2<DIM, 3*INNER, 64, 4>), dim3(B*12), dim3(256), 0, stream, h);
    hipLaunchKernelGGL((k_softmax2<INNER, DIM, 32, 8>), dim3(B*4), dim3(256), 0, stream, ow);
    hipLaunchKernelGGL(k_proj, dim3(B*25), dim3(768), 0, stream, x, h, qh, kh, vt);
    hipLaunchKernelGGL(k_attn4, dim3(38*32), dim3(256), 0, stream, qh, kh, vt, mask, ao);
    hipLaunchKernelGGL(k_final, dim3(B*50), dim3(128), 0, stream, ao, ow, out);
}

// Round 10
// 239.128 us; speedup vs baseline: 1.1946x; 1.1946x over previous
//
#include <hip/hip_runtime.h>
#include <hip/hip_bf16.h>
#include <math.h>

#define B 16
#define N 600
#define DIM 128
#define HEADS 8
#define DH 32
#define INNER 256
#define D3 384
#define NC_H (D3*INNER)   /* 98304 */
#define NC_O (INNER*DIM)  /* 32768 */

typedef _Float16 f16x8 __attribute__((ext_vector_type(8)));
typedef float    f32x4 __attribute__((ext_vector_type(4)));

// ---------------- ws layout (float offsets) ----------------  ws = 576 MiB
// h : 10240   ow : 1583104   t1 : 2107392   s1 : 2113536
// ao : 2117632   qh : 4575232(half)  kh : 5804032(half)  vt : 7032832(half)
// t2h: 8343552 (as half, [16][384])   s2h: 8346624 (as half, [16][256])
// pH : 8353792  (3 x 16 x 98304)      pO : 20936704 (4 x 16 x 32768)
// No aliasing anywhere.

__global__ void k_chain1(const float* __restrict__ resolution,
                         const float* __restrict__ framerate,
                         const float* __restrict__ W1, const float* __restrict__ b1,
                         const float* __restrict__ V1, const float* __restrict__ c1,
                         float* __restrict__ t1, float* __restrict__ s1)
{
    __shared__ float fr[B], re[B];
    int j = threadIdx.x;   // 384 threads
    if (j < B) { fr[j] = framerate[j]; re[j] = resolution[j]; }
    __syncthreads();
    {
        float w0 = W1[j], w1 = W1[D3 + j], bb = b1[j];
        for (int b = 0; b < B; ++b) t1[b*D3 + j] = fr[b]*w0 + re[b]*w1 + bb;
    }
    if (j < INNER) {
        float w0 = V1[j], w1 = V1[INNER + j], bb = c1[j];
        for (int b = 0; b < B; ++b) s1[b*INNER + j] = fr[b]*w0 + re[b]*w1 + bb;
    }
}

// second hypernet layer; outputs fp16 activations [16][K] for the MFMA GEMM
__global__ void k_chain2(const float* __restrict__ t1, const float* __restrict__ s1,
                         const float* __restrict__ W2, const float* __restrict__ b2,
                         const float* __restrict__ V2, const float* __restrict__ c2,
                         _Float16* __restrict__ t2h, _Float16* __restrict__ s2h)
{
    __shared__ float in_s[B*D3];
    int bid = blockIdx.x, tid = threadIdx.x;
    if (bid < 24) {
        for (int i = tid; i < B*D3; i += 256) in_s[i] = t1[i];
        __syncthreads();
        int flat = bid*256 + tid;
        int b = flat / D3, j = flat - b*D3;
        float acc = b2[j];
        #pragma unroll 4
        for (int kk = 0; kk < D3; ++kk)
            acc = fmaf(in_s[b*D3 + kk], W2[kk*D3 + j], acc);
        t2h[b*D3 + j] = (_Float16)acc;
    } else {
        for (int i = tid; i < B*INNER; i += 256) in_s[i] = s1[i];
        __syncthreads();
        int flat = (bid - 24)*256 + tid;
        int b = flat / INNER, j = flat - b*INNER;
        float acc = c2[j];
        #pragma unroll 4
        for (int kk = 0; kk < INNER; ++kk)
            acc = fmaf(in_s[b*INNER + kk], V2[kk*INNER + j], acc);
        s2h[b*INNER + j] = (_Float16)acc;
    }
}

static __device__ inline unsigned pk2(float a, float b) {
    auto t = __builtin_amdgcn_cvt_pkrtz(a, b);   // __fp16 ext_vector(2)
    return __builtin_bit_cast(unsigned, t);
}

// MFMA hypernet GEMM: out[b][col] = sum_k th[b][k] * W[k][col].
// Wave = 64 cols x KR k-rows; B-frags gathered straight from global f32 W
// (dword loads, 4x64B segments), cvt_pkrtz -> f16x8, mfma 16x16x32.
// No LDS, no barriers; 2-tile register pipeline (named sets, fully unrolled);
// up to 64 outstanding loads/wave.  A-frags (t2h fp16) preloaded, L1-hot.
#define LOADT(S, t) \
    _Pragma("unroll") for (int cc = 0; cc < 4; ++cc) { \
        _Pragma("unroll") for (int j = 0; j < 8; ++j) \
            S[cc*8+j] = Wp[(size_t)((t)*32 + g*8 + j)*NC + cc*16]; }

#define COMPT(S, t) \
    _Pragma("unroll") for (int cc = 0; cc < 4; ++cc) { \
        union { unsigned u[4]; f16x8 v; } bf; \
        bf.u[0] = pk2(S[cc*8+0], S[cc*8+1]); \
        bf.u[1] = pk2(S[cc*8+2], S[cc*8+3]); \
        bf.u[2] = pk2(S[cc*8+4], S[cc*8+5]); \
        bf.u[3] = pk2(S[cc*8+6], S[cc*8+7]); \
        acc[cc] = __builtin_amdgcn_mfma_f32_16x16x32_f16(af[(t)], bf.v, acc[cc], 0, 0, 0); }

template<int K, int NC, int KSG>
__global__ __launch_bounds__(256) void k_hgemm(const _Float16* __restrict__ th,
                                               const float* __restrict__ W,
                                               float* __restrict__ partial)
{
    constexpr int KR = K / KSG;       // 128 (W3) or 64 (V3)
    constexpr int TILES = KR / 32;    // 4 or 2
    constexpr int NCB = NC / 256;
    int tid = threadIdx.x;
    int w = tid >> 6, lane = tid & 63;
    int ql = lane & 15, g = lane >> 4;
    int cb = blockIdx.x % NCB, ksg = blockIdx.x / NCB;
    int colbase = cb*256 + w*64;
    const float* Wp = W + (size_t)(ksg*KR)*NC + colbase + ql;

    // A-frags: lane holds th[b=ql][ksg*KR + t*32 + g*8 .. +7]
    f16x8 af[TILES];
    #pragma unroll
    for (int t = 0; t < TILES; ++t)
        af[t] = *(const f16x8*)(th + ql*K + ksg*KR + t*32 + g*8);

    f32x4 acc[4];
    #pragma unroll
    for (int cc = 0; cc < 4; ++cc) acc[cc] = (f32x4){0.f, 0.f, 0.f, 0.f};

    float sA[32], sB[32];
    if constexpr (TILES == 4) {
        LOADT(sA, 0)
        LOADT(sB, 1)
        COMPT(sA, 0)
        LOADT(sA, 2)
        COMPT(sB, 1)
        LOADT(sB, 3)
        COMPT(sA, 2)
        COMPT(sB, 3)
    } else {
        LOADT(sA, 0)
        LOADT(sB, 1)
        COMPT(sA, 0)
        COMPT(sB, 1)
    }

    // D: row b = 4*g + r, col = colbase + cc*16 + ql
    float* pp = partial + (size_t)ksg*B*NC + colbase + ql;
    #pragma unroll
    for (int cc = 0; cc < 4; ++cc)
        #pragma unroll
        for (int r = 0; r < 4; ++r)
            pp[(size_t)(4*g + r)*NC + cc*16] = acc[cc][r];
}

template<int NC, int KSG>
__global__ __launch_bounds__(256) void k_reduce(const float* __restrict__ partial,
                                                const float* __restrict__ bias,
                                                float* __restrict__ out)
{
    int i = blockIdx.x*256 + threadIdx.x;
    int col = i % NC;
    float s = bias[col];
    #pragma unroll
    for (int ks = 0; ks < KSG; ++ks) s += partial[(size_t)ks*B*NC + i];
    out[i] = s;
}

// softmax along R-axis of data[b][R][CPB]; COLS*GROUPS = 256 threads
template<int R, int CPB, int COLS, int GROUPS>
__global__ __launch_bounds__(256) void k_softmax2(float* __restrict__ data)
{
    constexpr int RPT = R / GROUPS;
    __shared__ float red[GROUPS][COLS];
    int tid = threadIdx.x;
    int col = tid % COLS, g = tid / COLS;
    int nb = CPB / COLS;
    int b = blockIdx.x / nb, cb = blockIdx.x % nb;
    float* p = data + (size_t)b*R*CPB + (size_t)g*RPT*CPB + cb*COLS + col;
    float vals[RPT];
    float m = -1e30f;
    #pragma unroll 4
    for (int r = 0; r < RPT; ++r) { vals[r] = p[(size_t)r*CPB]; m = fmaxf(m, vals[r]); }
    red[g][col] = m;
    __syncthreads();
    float M = red[0][col];
    #pragma unroll
    for (int gg = 1; gg < GROUPS; ++gg) M = fmaxf(M, red[gg][col]);
    __syncthreads();
    float s = 0.f;
    #pragma unroll 4
    for (int r = 0; r < RPT; ++r) { vals[r] = __expf(vals[r] - M); s += vals[r]; }
    red[g][col] = s;
    __syncthreads();
    float S = 0.f;
    #pragma unroll
    for (int gg = 0; gg < GROUPS; ++gg) S += red[gg][col];
    float inv = 1.f / S;
    #pragma unroll 4
    for (int r = 0; r < RPT; ++r) p[(size_t)r*CPB] = vals[r] * inv;
}

// x @ qkvw -> q,k (fp16 row-major, q pre-scaled) and v (fp16 transposed [d][n])
__global__ __launch_bounds__(768) void k_proj(const float* __restrict__ x,
                                              const float* __restrict__ qkvw,
                                              _Float16* __restrict__ qh,
                                              _Float16* __restrict__ kh,
                                              _Float16* __restrict__ vt)
{
    __shared__ float4 xs4[24*32];
    int b = blockIdx.x / 25, t0 = (blockIdx.x % 25)*24;
    int tid = threadIdx.x;
    const float4* xp4 = (const float4*)(x + ((size_t)b*N + t0)*DIM);
    xs4[tid] = xp4[tid];              // 24*32 = 768 = blockDim
    __syncthreads();
    float acc[24];
    #pragma unroll
    for (int r = 0; r < 24; ++r) acc[r] = 0.f;
    const float* wp = qkvw + (size_t)b*NC_H + tid;
    for (int d4 = 0; d4 < 32; ++d4) {
        float w0 = wp[(size_t)(4*d4)*768];
        float w1 = wp[(size_t)(4*d4+1)*768];
        float w2 = wp[(size_t)(4*d4+2)*768];
        float w3 = wp[(size_t)(4*d4+3)*768];
        #pragma unroll
        for (int r = 0; r < 24; ++r) {
            float4 xv = xs4[r*32 + d4];
            acc[r] = fmaf(xv.x, w0, fmaf(xv.y, w1, fmaf(xv.z, w2, fmaf(xv.w, w3, acc[r]))));
        }
    }
    int which = tid >> 8;
    int e = tid & 255;
    int hh = e >> 5, dh = e & 31;
    const float scale = 0.17677669529663687f;   // 32^-0.5 folded into Q
    if (which == 0) {
        _Float16* qp = qh + ((size_t)(b*HEADS + hh)*N + t0)*DH + dh;
        #pragma unroll
        for (int r = 0; r < 24; ++r) qp[r*DH] = (_Float16)(acc[r]*scale);
    } else if (which == 1) {
        _Float16* kp = kh + ((size_t)(b*HEADS + hh)*N + t0)*DH + dh;
        #pragma unroll
        for (int r = 0; r < 24; ++r) kp[r*DH] = (_Float16)acc[r];
    } else {
        _Float16* vp = vt + ((size_t)(b*HEADS + hh)*DH + dh)*640 + t0;
        #pragma unroll
        for (int r = 0; r < 24; ++r) vp[r] = (_Float16)acc[r];
        if (t0 == 576) {
            // keep vt cols 600..639 deterministic zeros (PV tail contributes 0)
            #pragma unroll
            for (int r = 24; r < 64; ++r) vp[r] = (_Float16)0.f;
        }
    }
}

// MFMA flash attention v4.  Block = 4 waves = 4 heads sharing one (b, q-chunk);
// wave = 16 q-rows x 600 keys.  Head-independent mask tile [16][64] f32 staged
// cooperatively in LDS, double-buffered.  S^T = mfma(K, Q^T), out^T = mfma(V^T, P^T).
__global__ __launch_bounds__(256) void k_attn4(const _Float16* __restrict__ qh,
                                               const _Float16* __restrict__ kh,
                                               const _Float16* __restrict__ vt,
                                               const float* __restrict__ mask,
                                               float* __restrict__ ao)
{
    __shared__ float mbuf[2][16][65];
    __shared__ __align__(16) _Float16 plds[4][16][72];
    int bid = blockIdx.x;
    int qc = bid / 32, r2 = bid % 32;
    int b = r2 >> 1, hg = r2 & 1;
    int tid = threadIdx.x;
    int w = tid >> 6, lane = tid & 63;
    int ql = lane & 15, g = lane >> 4;
    int h = hg*4 + w;
    int q0 = qc*16;
    size_t bh = (size_t)(b*HEADS + h);
    const _Float16* Qb  = qh + bh*(size_t)(N*DH);
    const _Float16* Kb  = kh + bh*(size_t)(N*DH);
    const _Float16* Vtb = vt + bh*(size_t)(DH*640);

    int qrow = q0 + ql;
    int qr = qrow > 599 ? 599 : qrow;
    f16x8 qf = *(const f16x8*)(Qb + (size_t)qr*DH + g*8);

    int rl = w*4 + (lane >> 4);          // local tile row 0..15
    int mcol = (lane & 15)*4;            // float col 0..60
    int mgr = q0 + rl; if (mgr > 599) mgr = 599;
    const float* mgp = mask + ((size_t)b*N + mgr)*N;

    float M = -1e30f, S = 0.f;
    f32x4 acc[2];
    acc[0] = (f32x4){0.f,0.f,0.f,0.f};
    acc[1] = (f32x4){0.f,0.f,0.f,0.f};

    {
        int c0 = mcol; if (c0 > 596) c0 = 596;
        float4 mv = *(const float4*)(mgp + c0);
        mbuf[0][rl][mcol+0] = mv.x;
        mbuf[0][rl][mcol+1] = mv.y;
        mbuf[0][rl][mcol+2] = mv.z;
        mbuf[0][rl][mcol+3] = mv.w;
    }
    __syncthreads();

    for (int c = 0; c < 10; ++c) {
        int k0 = c*64;
        int cur = c & 1;
        float4 mnext;
        if (c < 9) {
            int cg = (c+1)*64 + mcol; if (cg > 596) cg = 596;
            mnext = *(const float4*)(mgp + cg);
        }
        f32x4 st[4];
        #pragma unroll
        for (int t = 0; t < 4; ++t) {
            int kr = k0 + 16*t + ql; if (kr > 599) kr = 599;
            f16x8 kf = *(const f16x8*)(Kb + (size_t)kr*DH + g*8);
            st[t] = __builtin_amdgcn_mfma_f32_16x16x32_f16(
                kf, qf, (f32x4){0.f,0.f,0.f,0.f}, 0, 0, 0);
        }
        float tm = -1e30f;
        #pragma unroll
        for (int t = 0; t < 4; ++t) {
            #pragma unroll
            for (int r = 0; r < 4; ++r) {
                int key = k0 + 16*t + 4*g + r;
                float sv = st[t][r];
                if (key >= N) sv = -1e30f;
                st[t][r] = sv;
                tm = fmaxf(tm, sv);
            }
        }
        tm = fmaxf(tm, __shfl_xor(tm, 16));
        tm = fmaxf(tm, __shfl_xor(tm, 32));
        float Mn = fmaxf(M, tm);
        float scl = __expf(M - Mn);
        M = Mn;
        S *= scl;
        acc[0] *= scl;
        acc[1] *= scl;
        float ssum = 0.f;
        #pragma unroll
        for (int t = 0; t < 4; ++t) {
            int cb4 = 16*t + 4*g;
            float e0 = __expf(st[t][0] - Mn);
            float e1 = __expf(st[t][1] - Mn);
            float e2 = __expf(st[t][2] - Mn);
            float e3 = __expf(st[t][3] - Mn);
            ssum += (e0 + e1) + (e2 + e3);
            float m0 = mbuf[cur][ql][cb4+0];
            float m1 = mbuf[cur][ql][cb4+1];
            float m2 = mbuf[cur][ql][cb4+2];
            float m3 = mbuf[cur][ql][cb4+3];
            *(unsigned*)&plds[w][ql][cb4]     = pk2(e0*m0, e1*m1);
            *(unsigned*)&plds[w][ql][cb4 + 2] = pk2(e2*m2, e3*m3);
        }
        ssum += __shfl_xor(ssum, 16);
        ssum += __shfl_xor(ssum, 32);
        S += ssum;
        #pragma unroll
        for (int win = 0; win < 2; ++win) {
            f16x8 pf = *(const f16x8*)&plds[w][ql][win*32 + g*8];
            #pragma unroll
            for (int dt = 0; dt < 2; ++dt) {
                f16x8 vf = *(const f16x8*)(Vtb + (size_t)(dt*16 + ql)*640 + k0 + win*32 + g*8);
                acc[dt] = __builtin_amdgcn_mfma_f32_16x16x32_f16(vf, pf, acc[dt], 0, 0, 0);
            }
        }
        if (c < 9) {
            int nb = cur ^ 1;
            mbuf[nb][rl][mcol+0] = mnext.x;
            mbuf[nb][rl][mcol+1] = mnext.y;
            mbuf[nb][rl][mcol+2] = mnext.z;
            mbuf[nb][rl][mcol+3] = mnext.w;
        }
        __syncthreads();
    }

    if (qrow < N) {
        float inv = 1.f / S;
        float* o = ao + ((size_t)b*N + qrow)*INNER + h*DH;
        #pragma unroll
        for (int dt = 0; dt < 2; ++dt)
            #pragma unroll
            for (int r = 0; r < 4; ++r)
                o[dt*16 + 4*g + r] = acc[dt][r] * inv;
    }
}

__global__ __launch_bounds__(128) void k_final(const float* __restrict__ ao,
                                               const float* __restrict__ ow,
                                               float* __restrict__ out)
{
    __shared__ float4 os4[12*64];
    int b = blockIdx.x / 50, t0 = (blockIdx.x % 50)*12;
    int tid = threadIdx.x;
    const float4* ap4 = (const float4*)(ao + ((size_t)b*N + t0)*INNER);
    for (int i = tid; i < 12*64; i += 128) os4[i] = ap4[i];
    __syncthreads();
    float acc[12];
    #pragma unroll
    for (int r = 0; r < 12; ++r) acc[r] = 0.f;
    const float* wp = ow + (size_t)b*NC_O + tid;
    for (int i4 = 0; i4 < 64; ++i4) {
        float w0 = wp[(size_t)(4*i4)*DIM];
        float w1 = wp[(size_t)(4*i4+1)*DIM];
        float w2 = wp[(size_t)(4*i4+2)*DIM];
        float w3 = wp[(size_t)(4*i4+3)*DIM];
        #pragma unroll
        for (int r = 0; r < 12; ++r) {
            float4 av = os4[r*64 + i4];
            acc[r] = fmaf(av.x, w0, fmaf(av.y, w1, fmaf(av.z, w2, fmaf(av.w, w3, acc[r]))));
        }
    }
    float* op = out + ((size_t)b*N + t0)*DIM + tid;
    #pragma unroll
    for (int r = 0; r < 12; ++r) op[r*DIM] = acc[r];
}

extern "C" void kernel_launch(void* const* d_in, const int* in_sizes, int n_in,
                              void* d_out, int out_size, void* d_ws, size_t ws_size,
                              hipStream_t stream)
{
    const float* x          = (const float*)d_in[0];
    const float* mask       = (const float*)d_in[1];
    const float* resolution = (const float*)d_in[2];
    const float* framerate  = (const float*)d_in[3];
    const float* W1 = (const float*)d_in[4];
    const float* b1 = (const float*)d_in[5];
    const float* W2 = (const float*)d_in[6];
    const float* b2 = (const float*)d_in[7];
    const float* W3 = (const float*)d_in[8];
    const float* b3 = (const float*)d_in[9];
    const float* V1 = (const float*)d_in[10];
    const float* c1 = (const float*)d_in[11];
    const float* V2 = (const float*)d_in[12];
    const float* c2 = (const float*)d_in[13];
    const float* V3 = (const float*)d_in[14];
    const float* c3 = (const float*)d_in[15];

    float* ws = (float*)d_ws;
    float* h   = ws + 10240;
    float* ow  = ws + 1583104;
    float* t1  = ws + 2107392;
    float* s1  = ws + 2113536;
    float* ao  = ws + 2117632;
    _Float16* qh  = (_Float16*)(ws + 4575232);
    _Float16* kh  = (_Float16*)(ws + 5804032);
    _Float16* vt  = (_Float16*)(ws + 7032832);
    _Float16* t2h = (_Float16*)(ws + 8343552);   // [16][384]
    _Float16* s2h = (_Float16*)(ws + 8346624);   // [16][256]
    float* pH  = ws + 8353792;              // 3 x 1,572,864
    float* pO  = ws + 20936704;             // 4 x 524,288
    float* out = (float*)d_out;

    hipLaunchKernelGGL(k_chain1, dim3(1), dim3(384), 0, stream,
                       resolution, framerate, W1, b1, V1, c1, t1, s1);
    hipLaunchKernelGGL(k_chain2, dim3(40), dim3(256), 0, stream,
                       t1, s1, W2, b2, V2, c2, t2h, s2h);
    hipLaunchKernelGGL((k_hgemm<D3, NC_H, 3>), dim3((NC_H/256)*3), dim3(256), 0, stream,
                       t2h, W3, pH);
    hipLaunchKernelGGL((k_hgemm<INNER, NC_O, 4>), dim3((NC_O/256)*4), dim3(256), 0, stream,
                       s2h, V3, pO);
    hipLaunchKernelGGL((k_reduce<NC_H, 3>), dim3(B*NC_H/256), dim3(256), 0, stream,
                       pH, b3, h);
    hipLaunchKernelGGL((k_reduce<NC_O, 4>), dim3(B*NC_O/256), dim3(256), 0, stream,
                       pO, c3, ow);
    hipLaunchKernelGGL((k_softmax2<DIM, 3*INNER, 64, 4>), dim3(B*12), dim3(256), 0, stream, h);
    hipLaunchKernelGGL((k_softmax2<INNER, DIM, 32, 8>), dim3(B*4), dim3(256), 0, stream, ow);
    hipLaunchKernelGGL(k_proj, dim3(B*25), dim3(768), 0, stream, x, h, qh, kh, vt);
    hipLaunchKernelGGL(k_attn4, dim3(38*32), dim3(256), 0, stream, qh, kh, vt, mask, ao);
    hipLaunchKernelGGL(k_final, dim3(B*50), dim3(128), 0, stream, ao, ow, out);
}

// Round 11
// 211.352 us; speedup vs baseline: 1.3516x; 1.1314x over previous
//
#include <hip/hip_runtime.h>
#include <hip/hip_bf16.h>
#include <math.h>

#define B 16
#define N 600
#define DIM 128
#define HEADS 8
#define DH 32
#define INNER 256
#define D3 384
#define NC_H (D3*INNER)   /* 98304 */
#define NC_O (INNER*DIM)  /* 32768 */

typedef _Float16 f16x8 __attribute__((ext_vector_type(8)));
typedef float    f32x4 __attribute__((ext_vector_type(4)));

// ---------------- ws layout (float offsets) ----------------  ws = 576 MiB
// h : 10240   ow : 1583104
// ao : 2117632   qh : 4575232(half)  kh : 5804032(half)  vt : 7032832(half)
// t2h: 8343552 (half, [16][384])   s2h: 8346624 (half, [16][256])
// pH : 8353792  (3 x 16 x 98304)   pO : 20936704 (4 x 16 x 32768)

// ---- fused hypernet layers 1+2: recompute t1/s1 in-block, GEMM -> fp16 ----
__global__ __launch_bounds__(256) void k_chain(const float* __restrict__ resolution,
                                               const float* __restrict__ framerate,
                                               const float* __restrict__ W1, const float* __restrict__ b1,
                                               const float* __restrict__ W2, const float* __restrict__ b2,
                                               const float* __restrict__ V1, const float* __restrict__ c1,
                                               const float* __restrict__ V2, const float* __restrict__ c2,
                                               _Float16* __restrict__ t2h, _Float16* __restrict__ s2h)
{
    __shared__ float fr[B], re[B];
    __shared__ float in_s[B*D3];
    int bid = blockIdx.x, tid = threadIdx.x;
    if (tid < B) { fr[tid] = framerate[tid]; re[tid] = resolution[tid]; }
    __syncthreads();
    if (bid < 24) {
        for (int i = tid; i < B*D3; i += 256) {
            int b = i / D3, j = i - b*D3;
            in_s[i] = fr[b]*W1[j] + re[b]*W1[D3 + j] + b1[j];
        }
        __syncthreads();
        int flat = bid*256 + tid;           // = b*384 + j
        int b = flat / D3, j = flat - b*D3;
        float acc = b2[j];
        #pragma unroll 4
        for (int kk = 0; kk < D3; ++kk)
            acc = fmaf(in_s[b*D3 + kk], W2[kk*D3 + j], acc);
        t2h[flat] = (_Float16)acc;
    } else {
        for (int i = tid; i < B*INNER; i += 256) {
            int b = i >> 8, j = i & 255;
            in_s[i] = fr[b]*V1[j] + re[b]*V1[INNER + j] + c1[j];
        }
        __syncthreads();
        int flat = (bid - 24)*256 + tid;    // = b*256 + j
        int b = flat >> 8, j = flat & 255;
        float acc = c2[j];
        #pragma unroll 4
        for (int kk = 0; kk < INNER; ++kk)
            acc = fmaf(in_s[b*INNER + kk], V2[kk*INNER + j], acc);
        s2h[flat] = (_Float16)acc;
    }
}

static __device__ inline unsigned pk2(float a, float b) {
    auto t = __builtin_amdgcn_cvt_pkrtz(a, b);   // __fp16 ext_vector(2)
    return __builtin_bit_cast(unsigned, t);
}

// MFMA hypernet GEMM body (see round-10 notes): wave = 64 cols, B-frags gathered
// from global f32 W (dword), cvt_pkrtz -> f16x8, mfma 16x16x32, no LDS/barriers.
#define LOADT(S, t) \
    _Pragma("unroll") for (int cc = 0; cc < 4; ++cc) { \
        _Pragma("unroll") for (int j = 0; j < 8; ++j) \
            S[cc*8+j] = Wp[(size_t)((t)*32 + g*8 + j)*NC + cc*16]; }

#define COMPT(S, t) \
    _Pragma("unroll") for (int cc = 0; cc < 4; ++cc) { \
        union { unsigned u[4]; f16x8 v; } bf; \
        bf.u[0] = pk2(S[cc*8+0], S[cc*8+1]); \
        bf.u[1] = pk2(S[cc*8+2], S[cc*8+3]); \
        bf.u[2] = pk2(S[cc*8+4], S[cc*8+5]); \
        bf.u[3] = pk2(S[cc*8+6], S[cc*8+7]); \
        acc[cc] = __builtin_amdgcn_mfma_f32_16x16x32_f16(af[(t)], bf.v, acc[cc], 0, 0, 0); }

template<int K, int NC, int KSG>
__device__ __forceinline__ void hgemm_body(int bidl, int tid,
                                           const _Float16* __restrict__ th,
                                           const float* __restrict__ W,
                                           float* __restrict__ partial)
{
    constexpr int KR = K / KSG;       // 128 (W3) or 64 (V3)
    constexpr int TILES = KR / 32;    // 4 or 2
    constexpr int NCB = NC / 256;
    int w = tid >> 6, lane = tid & 63;
    int ql = lane & 15, g = lane >> 4;
    int cb = bidl % NCB, ksg = bidl / NCB;
    int colbase = cb*256 + w*64;
    const float* Wp = W + (size_t)(ksg*KR)*NC + colbase + ql;

    f16x8 af[TILES];
    #pragma unroll
    for (int t = 0; t < TILES; ++t)
        af[t] = *(const f16x8*)(th + ql*K + ksg*KR + t*32 + g*8);

    f32x4 acc[4];
    #pragma unroll
    for (int cc = 0; cc < 4; ++cc) acc[cc] = (f32x4){0.f, 0.f, 0.f, 0.f};

    float sA[32], sB[32];
    if constexpr (TILES == 4) {
        LOADT(sA, 0)
        LOADT(sB, 1)
        COMPT(sA, 0)
        LOADT(sA, 2)
        COMPT(sB, 1)
        LOADT(sB, 3)
        COMPT(sA, 2)
        COMPT(sB, 3)
    } else {
        LOADT(sA, 0)
        LOADT(sB, 1)
        COMPT(sA, 0)
        COMPT(sB, 1)
    }

    float* pp = partial + (size_t)ksg*B*NC + colbase + ql;
    #pragma unroll
    for (int cc = 0; cc < 4; ++cc)
        #pragma unroll
        for (int r = 0; r < 4; ++r)
            pp[(size_t)(4*g + r)*NC + cc*16] = acc[cc][r];
}

#define NBH ((NC_H/256)*3)   /* 1152 */
#define NBO ((NC_O/256)*4)   /* 512 */

__global__ __launch_bounds__(256) void k_hgemm_all(const _Float16* __restrict__ t2h,
                                                   const _Float16* __restrict__ s2h,
                                                   const float* __restrict__ W3,
                                                   const float* __restrict__ V3,
                                                   float* __restrict__ pH,
                                                   float* __restrict__ pO)
{
    int bid = blockIdx.x, tid = threadIdx.x;
    if (bid < NBH) hgemm_body<D3, NC_H, 3>(bid, tid, t2h, W3, pH);
    else           hgemm_body<INNER, NC_O, 4>(bid - NBH, tid, s2h, V3, pO);
}

// ---- fused split-K reduce + bias + column softmax ----
// element [b][flat] = bias[flat] + sum_ks partial[ks][b][flat]; softmax over the
// R-axis (flat = r*CPB + c).  COLS*GROUPS = 256 threads.
template<int R, int CPB, int COLS, int GROUPS, int KSG, int NC>
__device__ __forceinline__ void smred_body(int bidl, int tid,
                                           const float* __restrict__ partial,
                                           const float* __restrict__ bias,
                                           float* __restrict__ outp,
                                           float* __restrict__ red)
{
    constexpr int RPT = R / GROUPS;
    int col = tid % COLS, g = tid / COLS;
    constexpr int nb = CPB / COLS;
    int b = bidl / nb, cb = bidl % nb;
    float vals[RPT];
    float m = -1e30f;
    #pragma unroll 4
    for (int r = 0; r < RPT; ++r) {
        int flat = (g*RPT + r)*CPB + cb*COLS + col;
        float s = bias[flat];
        #pragma unroll
        for (int ks = 0; ks < KSG; ++ks)
            s += partial[(size_t)ks*B*NC + (size_t)b*NC + flat];
        vals[r] = s;
        m = fmaxf(m, s);
    }
    red[g*COLS + col] = m;
    __syncthreads();
    float M = red[col];
    #pragma unroll
    for (int gg = 1; gg < GROUPS; ++gg) M = fmaxf(M, red[gg*COLS + col]);
    __syncthreads();
    float s = 0.f;
    #pragma unroll 4
    for (int r = 0; r < RPT; ++r) { vals[r] = __expf(vals[r] - M); s += vals[r]; }
    red[g*COLS + col] = s;
    __syncthreads();
    float S = 0.f;
    #pragma unroll
    for (int gg = 0; gg < GROUPS; ++gg) S += red[gg*COLS + col];
    float inv = 1.f / S;
    #pragma unroll 4
    for (int r = 0; r < RPT; ++r) {
        int flat = (g*RPT + r)*CPB + cb*COLS + col;
        outp[(size_t)b*NC + flat] = vals[r] * inv;
    }
}

#define NSH (B*24)   /* 384: h path, COLS=32 GROUPS=8 */
#define NSO (B*8)    /* 128: ow path, COLS=16 GROUPS=16 */

__global__ __launch_bounds__(256) void k_smred(const float* __restrict__ pH,
                                               const float* __restrict__ pO,
                                               const float* __restrict__ b3,
                                               const float* __restrict__ c3,
                                               float* __restrict__ h,
                                               float* __restrict__ ow)
{
    __shared__ float red[256];
    int bid = blockIdx.x, tid = threadIdx.x;
    if (bid < NSH) smred_body<DIM, 3*INNER, 32, 8, 3, NC_H>(bid, tid, pH, b3, h, red);
    else           smred_body<INNER, DIM, 16, 16, 4, NC_O>(bid - NSH, tid, pO, c3, ow, red);
}

// x @ qkvw -> q,k (fp16 row-major, q pre-scaled) and v (fp16 transposed [d][n])
__global__ __launch_bounds__(768) void k_proj(const float* __restrict__ x,
                                              const float* __restrict__ qkvw,
                                              _Float16* __restrict__ qh,
                                              _Float16* __restrict__ kh,
                                              _Float16* __restrict__ vt)
{
    __shared__ float4 xs4[24*32];
    int b = blockIdx.x / 25, t0 = (blockIdx.x % 25)*24;
    int tid = threadIdx.x;
    const float4* xp4 = (const float4*)(x + ((size_t)b*N + t0)*DIM);
    xs4[tid] = xp4[tid];              // 24*32 = 768 = blockDim
    __syncthreads();
    float acc[24];
    #pragma unroll
    for (int r = 0; r < 24; ++r) acc[r] = 0.f;
    const float* wp = qkvw + (size_t)b*NC_H + tid;
    for (int d4 = 0; d4 < 32; ++d4) {
        float w0 = wp[(size_t)(4*d4)*768];
        float w1 = wp[(size_t)(4*d4+1)*768];
        float w2 = wp[(size_t)(4*d4+2)*768];
        float w3 = wp[(size_t)(4*d4+3)*768];
        #pragma unroll
        for (int r = 0; r < 24; ++r) {
            float4 xv = xs4[r*32 + d4];
            acc[r] = fmaf(xv.x, w0, fmaf(xv.y, w1, fmaf(xv.z, w2, fmaf(xv.w, w3, acc[r]))));
        }
    }
    int which = tid >> 8;
    int e = tid & 255;
    int hh = e >> 5, dh = e & 31;
    const float scale = 0.17677669529663687f;   // 32^-0.5 folded into Q
    if (which == 0) {
        _Float16* qp = qh + ((size_t)(b*HEADS + hh)*N + t0)*DH + dh;
        #pragma unroll
        for (int r = 0; r < 24; ++r) qp[r*DH] = (_Float16)(acc[r]*scale);
    } else if (which == 1) {
        _Float16* kp = kh + ((size_t)(b*HEADS + hh)*N + t0)*DH + dh;
        #pragma unroll
        for (int r = 0; r < 24; ++r) kp[r*DH] = (_Float16)acc[r];
    } else {
        _Float16* vp = vt + ((size_t)(b*HEADS + hh)*DH + dh)*640 + t0;
        #pragma unroll
        for (int r = 0; r < 24; ++r) vp[r] = (_Float16)acc[r];
        if (t0 == 576) {
            // keep vt cols 600..639 deterministic zeros (PV tail contributes 0)
            #pragma unroll
            for (int r = 24; r < 64; ++r) vp[r] = (_Float16)0.f;
        }
    }
}

// MFMA flash attention v4.  Block = 4 waves = 4 heads sharing one (b, q-chunk);
// wave = 16 q-rows x 600 keys.  Head-independent mask tile [16][64] f32 staged
// cooperatively in LDS, double-buffered.  S^T = mfma(K, Q^T), out^T = mfma(V^T, P^T).
__global__ __launch_bounds__(256) void k_attn4(const _Float16* __restrict__ qh,
                                               const _Float16* __restrict__ kh,
                                               const _Float16* __restrict__ vt,
                                               const float* __restrict__ mask,
                                               float* __restrict__ ao)
{
    __shared__ float mbuf[2][16][65];
    __shared__ __align__(16) _Float16 plds[4][16][72];
    int bid = blockIdx.x;
    int qc = bid / 32, r2 = bid % 32;
    int b = r2 >> 1, hg = r2 & 1;
    int tid = threadIdx.x;
    int w = tid >> 6, lane = tid & 63;
    int ql = lane & 15, g = lane >> 4;
    int h = hg*4 + w;
    int q0 = qc*16;
    size_t bh = (size_t)(b*HEADS + h);
    const _Float16* Qb  = qh + bh*(size_t)(N*DH);
    const _Float16* Kb  = kh + bh*(size_t)(N*DH);
    const _Float16* Vtb = vt + bh*(size_t)(DH*640);

    int qrow = q0 + ql;
    int qr = qrow > 599 ? 599 : qrow;
    f16x8 qf = *(const f16x8*)(Qb + (size_t)qr*DH + g*8);

    int rl = w*4 + (lane >> 4);          // local tile row 0..15
    int mcol = (lane & 15)*4;            // float col 0..60
    int mgr = q0 + rl; if (mgr > 599) mgr = 599;
    const float* mgp = mask + ((size_t)b*N + mgr)*N;

    float M = -1e30f, S = 0.f;
    f32x4 acc[2];
    acc[0] = (f32x4){0.f,0.f,0.f,0.f};
    acc[1] = (f32x4){0.f,0.f,0.f,0.f};

    {
        int c0 = mcol; if (c0 > 596) c0 = 596;
        float4 mv = *(const float4*)(mgp + c0);
        mbuf[0][rl][mcol+0] = mv.x;
        mbuf[0][rl][mcol+1] = mv.y;
        mbuf[0][rl][mcol+2] = mv.z;
        mbuf[0][rl][mcol+3] = mv.w;
    }
    __syncthreads();

    for (int c = 0; c < 10; ++c) {
        int k0 = c*64;
        int cur = c & 1;
        float4 mnext;
        if (c < 9) {
            int cg = (c+1)*64 + mcol; if (cg > 596) cg = 596;
            mnext = *(const float4*)(mgp + cg);
        }
        f32x4 st[4];
        #pragma unroll
        for (int t = 0; t < 4; ++t) {
            int kr = k0 + 16*t + ql; if (kr > 599) kr = 599;
            f16x8 kf = *(const f16x8*)(Kb + (size_t)kr*DH + g*8);
            st[t] = __builtin_amdgcn_mfma_f32_16x16x32_f16(
                kf, qf, (f32x4){0.f,0.f,0.f,0.f}, 0, 0, 0);
        }
        float tm = -1e30f;
        #pragma unroll
        for (int t = 0; t < 4; ++t) {
            #pragma unroll
            for (int r = 0; r < 4; ++r) {
                int key = k0 + 16*t + 4*g + r;
                float sv = st[t][r];
                if (key >= N) sv = -1e30f;
                st[t][r] = sv;
                tm = fmaxf(tm, sv);
            }
        }
        tm = fmaxf(tm, __shfl_xor(tm, 16));
        tm = fmaxf(tm, __shfl_xor(tm, 32));
        float Mn = fmaxf(M, tm);
        float scl = __expf(M - Mn);
        M = Mn;
        S *= scl;
        acc[0] *= scl;
        acc[1] *= scl;
        float ssum = 0.f;
        #pragma unroll
        for (int t = 0; t < 4; ++t) {
            int cb4 = 16*t + 4*g;
            float e0 = __expf(st[t][0] - Mn);
            float e1 = __expf(st[t][1] - Mn);
            float e2 = __expf(st[t][2] - Mn);
            float e3 = __expf(st[t][3] - Mn);
            ssum += (e0 + e1) + (e2 + e3);
            float m0 = mbuf[cur][ql][cb4+0];
            float m1 = mbuf[cur][ql][cb4+1];
            float m2 = mbuf[cur][ql][cb4+2];
            float m3 = mbuf[cur][ql][cb4+3];
            *(unsigned*)&plds[w][ql][cb4]     = pk2(e0*m0, e1*m1);
            *(unsigned*)&plds[w][ql][cb4 + 2] = pk2(e2*m2, e3*m3);
        }
        ssum += __shfl_xor(ssum, 16);
        ssum += __shfl_xor(ssum, 32);
        S += ssum;
        #pragma unroll
        for (int win = 0; win < 2; ++win) {
            f16x8 pf = *(const f16x8*)&plds[w][ql][win*32 + g*8];
            #pragma unroll
            for (int dt = 0; dt < 2; ++dt) {
                f16x8 vf = *(const f16x8*)(Vtb + (size_t)(dt*16 + ql)*640 + k0 + win*32 + g*8);
                acc[dt] = __builtin_amdgcn_mfma_f32_16x16x32_f16(vf, pf, acc[dt], 0, 0, 0);
            }
        }
        if (c < 9) {
            int nb = cur ^ 1;
            mbuf[nb][rl][mcol+0] = mnext.x;
            mbuf[nb][rl][mcol+1] = mnext.y;
            mbuf[nb][rl][mcol+2] = mnext.z;
            mbuf[nb][rl][mcol+3] = mnext.w;
        }
        __syncthreads();
    }

    if (qrow < N) {
        float inv = 1.f / S;
        float* o = ao + ((size_t)b*N + qrow)*INNER + h*DH;
        #pragma unroll
        for (int dt = 0; dt < 2; ++dt)
            #pragma unroll
            for (int r = 0; r < 4; ++r)
                o[dt*16 + 4*g + r] = acc[dt][r] * inv;
    }
}

__global__ __launch_bounds__(128) void k_final(const float* __restrict__ ao,
                                               const float* __restrict__ ow,
                                               float* __restrict__ out)
{
    __shared__ float4 os4[12*64];
    int b = blockIdx.x / 50, t0 = (blockIdx.x % 50)*12;
    int tid = threadIdx.x;
    const float4* ap4 = (const float4*)(ao + ((size_t)b*N + t0)*INNER);
    for (int i = tid; i < 12*64; i += 128) os4[i] = ap4[i];
    __syncthreads();
    float acc[12];
    #pragma unroll
    for (int r = 0; r < 12; ++r) acc[r] = 0.f;
    const float* wp = ow + (size_t)b*NC_O + tid;
    for (int i4 = 0; i4 < 64; ++i4) {
        float w0 = wp[(size_t)(4*i4)*DIM];
        float w1 = wp[(size_t)(4*i4+1)*DIM];
        float w2 = wp[(size_t)(4*i4+2)*DIM];
        float w3 = wp[(size_t)(4*i4+3)*DIM];
        #pragma unroll
        for (int r = 0; r < 12; ++r) {
            float4 av = os4[r*64 + i4];
            acc[r] = fmaf(av.x, w0, fmaf(av.y, w1, fmaf(av.z, w2, fmaf(av.w, w3, acc[r]))));
        }
    }
    float* op = out + ((size_t)b*N + t0)*DIM + tid;
    #pragma unroll
    for (int r = 0; r < 12; ++r) op[r*DIM] = acc[r];
}

extern "C" void kernel_launch(void* const* d_in, const int* in_sizes, int n_in,
                              void* d_out, int out_size, void* d_ws, size_t ws_size,
                              hipStream_t stream)
{
    const float* x          = (const float*)d_in[0];
    const float* mask       = (const float*)d_in[1];
    const float* resolution = (const float*)d_in[2];
    const float* framerate  = (const float*)d_in[3];
    const float* W1 = (const float*)d_in[4];
    const float* b1 = (const float*)d_in[5];
    const float* W2 = (const float*)d_in[6];
    const float* b2 = (const float*)d_in[7];
    const float* W3 = (const float*)d_in[8];
    const float* b3 = (const float*)d_in[9];
    const float* V1 = (const float*)d_in[10];
    const float* c1 = (const float*)d_in[11];
    const float* V2 = (const float*)d_in[12];
    const float* c2 = (const float*)d_in[13];
    const float* V3 = (const float*)d_in[14];
    const float* c3 = (const float*)d_in[15];

    float* ws = (float*)d_ws;
    float* h   = ws + 10240;
    float* ow  = ws + 1583104;
    float* ao  = ws + 2117632;
    _Float16* qh  = (_Float16*)(ws + 4575232);
    _Float16* kh  = (_Float16*)(ws + 5804032);
    _Float16* vt  = (_Float16*)(ws + 7032832);
    _Float16* t2h = (_Float16*)(ws + 8343552);   // [16][384]
    _Float16* s2h = (_Float16*)(ws + 8346624);   // [16][256]
    float* pH  = ws + 8353792;              // 3 x 1,572,864
    float* pO  = ws + 20936704;             // 4 x 524,288
    float* out = (float*)d_out;

    hipLaunchKernelGGL(k_chain, dim3(40), dim3(256), 0, stream,
                       resolution, framerate, W1, b1, W2, b2, V1, c1, V2, c2, t2h, s2h);
    hipLaunchKernelGGL(k_hgemm_all, dim3(NBH + NBO), dim3(256), 0, stream,
                       t2h, s2h, W3, V3, pH, pO);
    hipLaunchKernelGGL(k_smred, dim3(NSH + NSO), dim3(256), 0, stream,
                       pH, pO, b3, c3, h, ow);
    hipLaunchKernelGGL(k_proj, dim3(B*25), dim3(768), 0, stream, x, h, qh, kh, vt);
    hipLaunchKernelGGL(k_attn4, dim3(38*32), dim3(256), 0, stream, qh, kh, vt, mask, ao);
    hipLaunchKernelGGL(k_final, dim3(B*50), dim3(128), 0, stream, ao, ow, out);
}

// Round 12
// 159.769 us; speedup vs baseline: 1.7879x; 1.3229x over previous
//
#include <hip/hip_runtime.h>
#include <hip/hip_bf16.h>
#include <math.h>

#define B 16
#define N 600
#define DIM 128
#define HEADS 8
#define DH 32
#define INNER 256
#define D3 384
#define NC_H (D3*INNER)   /* 98304 */
#define NC_O (INNER*DIM)  /* 32768 */

typedef _Float16 f16x8 __attribute__((ext_vector_type(8)));
typedef float    f32x4 __attribute__((ext_vector_type(4)));

// ---------------- ws layout (float offsets) ----------------  ws = 576 MiB
// hh : 10240   (half, [16][768][128] qkvw softmaxed, TRANSPOSED [e][d])
// ow : 1583104 (f32,  [16][256][128])
// ao : 2117632   qh : 4575232(half)  kh : 5804032(half)  vt : 7032832(half)
// t2h: 8343552 (half, [16][384])   s2h: 8346624 (half, [16][256])
// xh : 8348672 (half, [16][600][128])  ends 8963072
// pH : 8963072  (2 x 16 x 98304)   pO : 12108800 (4 x 16 x 32768)  end 14205952

// ---- fused hypernet layers 1+2 (blocks 0..39) + x->fp16 convert (40..103) ----
__global__ __launch_bounds__(256) void k_chain(const float* __restrict__ resolution,
                                               const float* __restrict__ framerate,
                                               const float* __restrict__ W1, const float* __restrict__ b1,
                                               const float* __restrict__ W2, const float* __restrict__ b2,
                                               const float* __restrict__ V1, const float* __restrict__ c1,
                                               const float* __restrict__ V2, const float* __restrict__ c2,
                                               const float* __restrict__ x,
                                               _Float16* __restrict__ t2h, _Float16* __restrict__ s2h,
                                               _Float16* __restrict__ xh)
{
    __shared__ float fr[B], re[B];
    __shared__ float in_s[B*D3];
    int bid = blockIdx.x, tid = threadIdx.x;
    if (bid >= 40) {        // x -> fp16 (RNE scalar casts)
        const float4* x4 = (const float4*)x;
        uint2* xo = (uint2*)xh;
        for (int i = (bid - 40)*256 + tid; i < B*N*DIM/4; i += 64*256) {
            float4 v = x4[i];
            union { _Float16 h[4]; uint2 u; } pk;
            pk.h[0] = (_Float16)v.x; pk.h[1] = (_Float16)v.y;
            pk.h[2] = (_Float16)v.z; pk.h[3] = (_Float16)v.w;
            xo[i] = pk.u;
        }
        return;
    }
    if (tid < B) { fr[tid] = framerate[tid]; re[tid] = resolution[tid]; }
    __syncthreads();
    if (bid < 24) {
        for (int i = tid; i < B*D3; i += 256) {
            int b = i / D3, j = i - b*D3;
            in_s[i] = fr[b]*W1[j] + re[b]*W1[D3 + j] + b1[j];
        }
        __syncthreads();
        int flat = bid*256 + tid;           // = b*384 + j
        int b = flat / D3, j = flat - b*D3;
        float acc = b2[j];
        #pragma unroll 4
        for (int kk = 0; kk < D3; ++kk)
            acc = fmaf(in_s[b*D3 + kk], W2[kk*D3 + j], acc);
        t2h[flat] = (_Float16)acc;
    } else {
        for (int i = tid; i < B*INNER; i += 256) {
            int b = i >> 8, j = i & 255;
            in_s[i] = fr[b]*V1[j] + re[b]*V1[INNER + j] + c1[j];
        }
        __syncthreads();
        int flat = (bid - 24)*256 + tid;    // = b*256 + j
        int b = flat >> 8, j = flat & 255;
        float acc = c2[j];
        #pragma unroll 4
        for (int kk = 0; kk < INNER; ++kk)
            acc = fmaf(in_s[b*INNER + kk], V2[kk*INNER + j], acc);
        s2h[flat] = (_Float16)acc;
    }
}

static __device__ inline unsigned pk2(float a, float b) {
    auto t = __builtin_amdgcn_cvt_pkrtz(a, b);   // __fp16 ext_vector(2)
    return __builtin_bit_cast(unsigned, t);
}

// MFMA hypernet GEMM: wave = 64 cols, B-frags gathered from global f32 W
// (dword), cvt_pkrtz -> f16x8, mfma 16x16x32, no LDS/barriers, 2-deep pipeline.
#define LOADT(S, t) \
    _Pragma("unroll") for (int cc = 0; cc < 4; ++cc) { \
        _Pragma("unroll") for (int j = 0; j < 8; ++j) \
            S[cc*8+j] = Wp[(size_t)((t)*32 + g*8 + j)*NC + cc*16]; }

#define COMPT(S, t) \
    _Pragma("unroll") for (int cc = 0; cc < 4; ++cc) { \
        union { unsigned u[4]; f16x8 v; } bf; \
        bf.u[0] = pk2(S[cc*8+0], S[cc*8+1]); \
        bf.u[1] = pk2(S[cc*8+2], S[cc*8+3]); \
        bf.u[2] = pk2(S[cc*8+4], S[cc*8+5]); \
        bf.u[3] = pk2(S[cc*8+6], S[cc*8+7]); \
        acc[cc] = __builtin_amdgcn_mfma_f32_16x16x32_f16(af[(t)], bf.v, acc[cc], 0, 0, 0); }

template<int K, int NC, int KSG>
__device__ __forceinline__ void hgemm_body(int bidl, int tid,
                                           const _Float16* __restrict__ th,
                                           const float* __restrict__ W,
                                           float* __restrict__ partial)
{
    constexpr int KR = K / KSG;       // 192 (W3) or 64 (V3)
    constexpr int TILES = KR / 32;    // 6 or 2 (even)
    constexpr int NCB = NC / 256;
    int w = tid >> 6, lane = tid & 63;
    int ql = lane & 15, g = lane >> 4;
    int cb = bidl % NCB, ksg = bidl / NCB;
    int colbase = cb*256 + w*64;
    const float* Wp = W + (size_t)(ksg*KR)*NC + colbase + ql;

    f16x8 af[TILES];
    #pragma unroll
    for (int t = 0; t < TILES; ++t)
        af[t] = *(const f16x8*)(th + ql*K + ksg*KR + t*32 + g*8);

    f32x4 acc[4];
    #pragma unroll
    for (int cc = 0; cc < 4; ++cc) acc[cc] = (f32x4){0.f, 0.f, 0.f, 0.f};

    float sA[32], sB[32];
    LOADT(sA, 0)
    LOADT(sB, 1)
    #pragma unroll
    for (int t = 0; t < TILES; t += 2) {
        COMPT(sA, t)
        if (t + 2 < TILES) LOADT(sA, t+2)
        COMPT(sB, t+1)
        if (t + 3 < TILES) LOADT(sB, t+3)
    }

    float* pp = partial + (size_t)ksg*B*NC + colbase + ql;
    #pragma unroll
    for (int cc = 0; cc < 4; ++cc)
        #pragma unroll
        for (int r = 0; r < 4; ++r)
            pp[(size_t)(4*g + r)*NC + cc*16] = acc[cc][r];
}

#define NBH ((NC_H/256)*2)   /* 768 */
#define NBO ((NC_O/256)*4)   /* 512 */

__global__ __launch_bounds__(256) void k_hgemm_all(const _Float16* __restrict__ t2h,
                                                   const _Float16* __restrict__ s2h,
                                                   const float* __restrict__ W3,
                                                   const float* __restrict__ V3,
                                                   float* __restrict__ pH,
                                                   float* __restrict__ pO)
{
    int bid = blockIdx.x, tid = threadIdx.x;
    if (bid < NBH) hgemm_body<D3, NC_H, 2>(bid, tid, t2h, W3, pH);
    else           hgemm_body<INNER, NC_O, 4>(bid - NBH, tid, s2h, V3, pO);
}

// ---- fused split-K reduce + bias + column softmax (optional transposed fp16 out) ----
template<int R, int CPB, int COLS, int GROUPS, int KSG, int NC, bool TR, typename OT>
__device__ __forceinline__ void smred_body(int bidl, int tid,
                                           const float* __restrict__ partial,
                                           const float* __restrict__ bias,
                                           OT* __restrict__ outp,
                                           float* __restrict__ red)
{
    constexpr int RPT = R / GROUPS;
    int col = tid % COLS, g = tid / COLS;
    constexpr int nb = CPB / COLS;
    int b = bidl / nb, cb = bidl % nb;
    int e = cb*COLS + col;
    float vals[RPT];
    float m = -1e30f;
    #pragma unroll 4
    for (int r = 0; r < RPT; ++r) {
        int flat = (g*RPT + r)*CPB + e;
        float s = bias[flat];
        #pragma unroll
        for (int ks = 0; ks < KSG; ++ks)
            s += partial[(size_t)ks*B*NC + (size_t)b*NC + flat];
        vals[r] = s;
        m = fmaxf(m, s);
    }
    red[g*COLS + col] = m;
    __syncthreads();
    float M = red[col];
    #pragma unroll
    for (int gg = 1; gg < GROUPS; ++gg) M = fmaxf(M, red[gg*COLS + col]);
    __syncthreads();
    float s = 0.f;
    #pragma unroll 4
    for (int r = 0; r < RPT; ++r) { vals[r] = __expf(vals[r] - M); s += vals[r]; }
    red[g*COLS + col] = s;
    __syncthreads();
    float S = 0.f;
    #pragma unroll
    for (int gg = 0; gg < GROUPS; ++gg) S += red[gg*COLS + col];
    float inv = 1.f / S;
    #pragma unroll 4
    for (int r = 0; r < RPT; ++r) {
        if constexpr (TR)
            outp[(size_t)b*NC + (size_t)e*R + (g*RPT + r)] = (OT)(vals[r] * inv);
        else
            outp[(size_t)b*NC + (size_t)(g*RPT + r)*CPB + e] = (OT)(vals[r] * inv);
    }
}

#define NSH (B*24)   /* 384: h path  (R=128 over d, CPB=768) -> hh fp16 [e][d] */
#define NSO (B*8)    /* 128: ow path (R=256 over e, CPB=128) -> ow f32 */

__global__ __launch_bounds__(256) void k_smred(const float* __restrict__ pH,
                                               const float* __restrict__ pO,
                                               const float* __restrict__ b3,
                                               const float* __restrict__ c3,
                                               _Float16* __restrict__ hh,
                                               float* __restrict__ ow)
{
    __shared__ float red[256];
    int bid = blockIdx.x, tid = threadIdx.x;
    if (bid < NSH) smred_body<DIM, 3*INNER, 32, 8, 2, NC_H, true, _Float16>(bid, tid, pH, b3, hh, red);
    else           smred_body<INNER, DIM, 16, 16, 4, NC_O, false, float>(bid - NSH, tid, pO, c3, ow, red);
}

// ---- MFMA projection: y[n][e] = sum_d x[n][d] * qkvw[d][e] ----
// Block = (b, 16-row chunk), 4 waves x 12 col-tiles (48 tiles = 768 cols).
// A-frag xf: lane ql = row n; B-frag wf: lane ql = col e (hh transposed [e][d]).
// q/k tiles: mfma(xf, wf) -> col=e, row=n (row-major out).
// v tiles:   mfma(wf, xf) -> col=n, row=e (transposed out) -- same frags, swapped.
__global__ __launch_bounds__(256) void k_projm(const _Float16* __restrict__ xh,
                                               const _Float16* __restrict__ hh,
                                               _Float16* __restrict__ qh,
                                               _Float16* __restrict__ kh,
                                               _Float16* __restrict__ vt)
{
    int bid = blockIdx.x;               // 16 b x 38 chunks
    int b = bid / 38, cn = bid % 38;
    int n0 = cn * 16;
    int tid = threadIdx.x;
    int w = tid >> 6, lane = tid & 63;
    int ql = lane & 15, g = lane >> 4;

    const _Float16* xb = xh + (size_t)b*N*DIM;
    const _Float16* hb = hh + (size_t)b*NC_H;

    int nl = n0 + ql; if (nl > 599) nl = 599;
    f16x8 xf[4];
    #pragma unroll
    for (int kt = 0; kt < 4; ++kt)
        xf[kt] = *(const f16x8*)(xb + (size_t)nl*DIM + kt*32 + g*8);

    const float scale = 0.17677669529663687f;   // 32^-0.5 folded into q
    #pragma unroll
    for (int j = 0; j < 12; ++j) {
        int ct = w*12 + j;              // 0..47
        int type = ct >> 4;             // 0=q, 1=k, 2=v
        int e0 = (ct & 15) * 16;        // col base within its 256-group
        f16x8 wf[4];
        #pragma unroll
        for (int kt = 0; kt < 4; ++kt)
            wf[kt] = *(const f16x8*)(hb + (size_t)(ct*16 + ql)*DIM + kt*32 + g*8);
        f32x4 acc = (f32x4){0.f, 0.f, 0.f, 0.f};
        if (type == 2) {
            #pragma unroll
            for (int kt = 0; kt < 4; ++kt)
                acc = __builtin_amdgcn_mfma_f32_16x16x32_f16(wf[kt], xf[kt], acc, 0, 0, 0);
            int n = n0 + ql;
            if (n < 600) {
                #pragma unroll
                for (int r = 0; r < 4; ++r) {
                    int e = e0 + 4*g + r;
                    vt[((size_t)(b*HEADS + (e>>5))*DH + (e&31))*640 + n] = (_Float16)acc[r];
                }
            }
        } else {
            #pragma unroll
            for (int kt = 0; kt < 4; ++kt)
                acc = __builtin_amdgcn_mfma_f32_16x16x32_f16(xf[kt], wf[kt], acc, 0, 0, 0);
            int e = e0 + ql;
            int head = e >> 5, dh = e & 31;
            _Float16* dst = (type == 0 ? qh : kh);
            float scl = (type == 0) ? scale : 1.f;
            #pragma unroll
            for (int r = 0; r < 4; ++r) {
                int n = n0 + 4*g + r;
                if (n < 600)
                    dst[((size_t)(b*HEADS + head)*N + n)*DH + dh] = (_Float16)(acc[r]*scl);
            }
        }
    }
    // vt tail cols 600..639: never written above; first (pre-poison) correctness
    // call could leave NaN fp16 patterns there -> 0*NaN = NaN in PV.  Zero-fill.
    if (cn == 37) {
        _Float16* vp = vt + ((size_t)b*256 + tid)*640;
        #pragma unroll
        for (int c = 600; c < 640; ++c) vp[c] = (_Float16)0.f;
    }
}

// MFMA flash attention v4 (unchanged).
__global__ __launch_bounds__(256) void k_attn4(const _Float16* __restrict__ qh,
                                               const _Float16* __restrict__ kh,
                                               const _Float16* __restrict__ vt,
                                               const float* __restrict__ mask,
                                               float* __restrict__ ao)
{
    __shared__ float mbuf[2][16][65];
    __shared__ __align__(16) _Float16 plds[4][16][72];
    int bid = blockIdx.x;
    int qc = bid / 32, r2 = bid % 32;
    int b = r2 >> 1, hg = r2 & 1;
    int tid = threadIdx.x;
    int w = tid >> 6, lane = tid & 63;
    int ql = lane & 15, g = lane >> 4;
    int h = hg*4 + w;
    int q0 = qc*16;
    size_t bh = (size_t)(b*HEADS + h);
    const _Float16* Qb  = qh + bh*(size_t)(N*DH);
    const _Float16* Kb  = kh + bh*(size_t)(N*DH);
    const _Float16* Vtb = vt + bh*(size_t)(DH*640);

    int qrow = q0 + ql;
    int qr = qrow > 599 ? 599 : qrow;
    f16x8 qf = *(const f16x8*)(Qb + (size_t)qr*DH + g*8);

    int rl = w*4 + (lane >> 4);
    int mcol = (lane & 15)*4;
    int mgr = q0 + rl; if (mgr > 599) mgr = 599;
    const float* mgp = mask + ((size_t)b*N + mgr)*N;

    float M = -1e30f, S = 0.f;
    f32x4 acc[2];
    acc[0] = (f32x4){0.f,0.f,0.f,0.f};
    acc[1] = (f32x4){0.f,0.f,0.f,0.f};

    {
        int c0 = mcol; if (c0 > 596) c0 = 596;
        float4 mv = *(const float4*)(mgp + c0);
        mbuf[0][rl][mcol+0] = mv.x;
        mbuf[0][rl][mcol+1] = mv.y;
        mbuf[0][rl][mcol+2] = mv.z;
        mbuf[0][rl][mcol+3] = mv.w;
    }
    __syncthreads();

    for (int c = 0; c < 10; ++c) {
        int k0 = c*64;
        int cur = c & 1;
        float4 mnext;
        if (c < 9) {
            int cg = (c+1)*64 + mcol; if (cg > 596) cg = 596;
            mnext = *(const float4*)(mgp + cg);
        }
        f32x4 st[4];
        #pragma unroll
        for (int t = 0; t < 4; ++t) {
            int kr = k0 + 16*t + ql; if (kr > 599) kr = 599;
            f16x8 kf = *(const f16x8*)(Kb + (size_t)kr*DH + g*8);
            st[t] = __builtin_amdgcn_mfma_f32_16x16x32_f16(
                kf, qf, (f32x4){0.f,0.f,0.f,0.f}, 0, 0, 0);
        }
        float tm = -1e30f;
        #pragma unroll
        for (int t = 0; t < 4; ++t) {
            #pragma unroll
            for (int r = 0; r < 4; ++r) {
                int key = k0 + 16*t + 4*g + r;
                float sv = st[t][r];
                if (key >= N) sv = -1e30f;
                st[t][r] = sv;
                tm = fmaxf(tm, sv);
            }
        }
        tm = fmaxf(tm, __shfl_xor(tm, 16));
        tm = fmaxf(tm, __shfl_xor(tm, 32));
        float Mn = fmaxf(M, tm);
        float scl = __expf(M - Mn);
        M = Mn;
        S *= scl;
        acc[0] *= scl;
        acc[1] *= scl;
        float ssum = 0.f;
        #pragma unroll
        for (int t = 0; t < 4; ++t) {
            int cb4 = 16*t + 4*g;
            float e0 = __expf(st[t][0] - Mn);
            float e1 = __expf(st[t][1] - Mn);
            float e2 = __expf(st[t][2] - Mn);
            float e3 = __expf(st[t][3] - Mn);
            ssum += (e0 + e1) + (e2 + e3);
            float m0 = mbuf[cur][ql][cb4+0];
            float m1 = mbuf[cur][ql][cb4+1];
            float m2 = mbuf[cur][ql][cb4+2];
            float m3 = mbuf[cur][ql][cb4+3];
            *(unsigned*)&plds[w][ql][cb4]     = pk2(e0*m0, e1*m1);
            *(unsigned*)&plds[w][ql][cb4 + 2] = pk2(e2*m2, e3*m3);
        }
        ssum += __shfl_xor(ssum, 16);
        ssum += __shfl_xor(ssum, 32);
        S += ssum;
        #pragma unroll
        for (int win = 0; win < 2; ++win) {
            f16x8 pf = *(const f16x8*)&plds[w][ql][win*32 + g*8];
            #pragma unroll
            for (int dt = 0; dt < 2; ++dt) {
                f16x8 vf = *(const f16x8*)(Vtb + (size_t)(dt*16 + ql)*640 + k0 + win*32 + g*8);
                acc[dt] = __builtin_amdgcn_mfma_f32_16x16x32_f16(vf, pf, acc[dt], 0, 0, 0);
            }
        }
        if (c < 9) {
            int nb = cur ^ 1;
            mbuf[nb][rl][mcol+0] = mnext.x;
            mbuf[nb][rl][mcol+1] = mnext.y;
            mbuf[nb][rl][mcol+2] = mnext.z;
            mbuf[nb][rl][mcol+3] = mnext.w;
        }
        __syncthreads();
    }

    if (qrow < N) {
        float inv = 1.f / S;
        float* o = ao + ((size_t)b*N + qrow)*INNER + h*DH;
        #pragma unroll
        for (int dt = 0; dt < 2; ++dt)
            #pragma unroll
            for (int r = 0; r < 4; ++r)
                o[dt*16 + 4*g + r] = acc[dt][r] * inv;
    }
}

__global__ __launch_bounds__(128) void k_final(const float* __restrict__ ao,
                                               const float* __restrict__ ow,
                                               float* __restrict__ out)
{
    __shared__ float4 os4[6*64];
    int b = blockIdx.x / 100, t0 = (blockIdx.x % 100)*6;
    int tid = threadIdx.x;
    const float4* ap4 = (const float4*)(ao + ((size_t)b*N + t0)*INNER);
    for (int i = tid; i < 6*64; i += 128) os4[i] = ap4[i];
    __syncthreads();
    float acc[6];
    #pragma unroll
    for (int r = 0; r < 6; ++r) acc[r] = 0.f;
    const float* wp = ow + (size_t)b*NC_O + tid;
    for (int i4 = 0; i4 < 64; ++i4) {
        float w0 = wp[(size_t)(4*i4)*DIM];
        float w1 = wp[(size_t)(4*i4+1)*DIM];
        float w2 = wp[(size_t)(4*i4+2)*DIM];
        float w3 = wp[(size_t)(4*i4+3)*DIM];
        #pragma unroll
        for (int r = 0; r < 6; ++r) {
            float4 av = os4[r*64 + i4];
            acc[r] = fmaf(av.x, w0, fmaf(av.y, w1, fmaf(av.z, w2, fmaf(av.w, w3, acc[r]))));
        }
    }
    float* op = out + ((size_t)b*N + t0)*DIM + tid;
    #pragma unroll
    for (int r = 0; r < 6; ++r) op[r*DIM] = acc[r];
}

extern "C" void kernel_launch(void* const* d_in, const int* in_sizes, int n_in,
                              void* d_out, int out_size, void* d_ws, size_t ws_size,
                              hipStream_t stream)
{
    const float* x          = (const float*)d_in[0];
    const float* mask       = (const float*)d_in[1];
    const float* resolution = (const float*)d_in[2];
    const float* framerate  = (const float*)d_in[3];
    const float* W1 = (const float*)d_in[4];
    const float* b1 = (const float*)d_in[5];
    const float* W2 = (const float*)d_in[6];
    const float* b2 = (const float*)d_in[7];
    const float* W3 = (const float*)d_in[8];
    const float* b3 = (const float*)d_in[9];
    const float* V1 = (const float*)d_in[10];
    const float* c1 = (const float*)d_in[11];
    const float* V2 = (const float*)d_in[12];
    const float* c2 = (const float*)d_in[13];
    const float* V3 = (const float*)d_in[14];
    const float* c3 = (const float*)d_in[15];

    float* ws = (float*)d_ws;
    _Float16* hh  = (_Float16*)(ws + 10240);     // [16][768][128]
    float* ow  = ws + 1583104;
    float* ao  = ws + 2117632;
    _Float16* qh  = (_Float16*)(ws + 4575232);
    _Float16* kh  = (_Float16*)(ws + 5804032);
    _Float16* vt  = (_Float16*)(ws + 7032832);
    _Float16* t2h = (_Float16*)(ws + 8343552);   // [16][384]
    _Float16* s2h = (_Float16*)(ws + 8346624);   // [16][256]
    _Float16* xh  = (_Float16*)(ws + 8348672);   // [16][600][128]
    float* pH  = ws + 8963072;              // 2 x 1,572,864
    float* pO  = ws + 12108800;             // 4 x 524,288
    float* out = (float*)d_out;

    hipLaunchKernelGGL(k_chain, dim3(104), dim3(256), 0, stream,
                       resolution, framerate, W1, b1, W2, b2, V1, c1, V2, c2,
                       x, t2h, s2h, xh);
    hipLaunchKernelGGL(k_hgemm_all, dim3(NBH + NBO), dim3(256), 0, stream,
                       t2h, s2h, W3, V3, pH, pO);
    hipLaunchKernelGGL(k_smred, dim3(NSH + NSO), dim3(256), 0, stream,
                       pH, pO, b3, c3, hh, ow);
    hipLaunchKernelGGL(k_projm, dim3(B*38), dim3(256), 0, stream,
                       xh, hh, qh, kh, vt);
    hipLaunchKernelGGL(k_attn4, dim3(38*32), dim3(256), 0, stream, qh, kh, vt, mask, ao);
    hipLaunchKernelGGL(k_final, dim3(B*100), dim3(128), 0, stream, ao, ow, out);
}